// Round 4
// baseline (640.957 us; speedup 1.0000x reference)
//
#include <hip/hip_runtime.h>

typedef __attribute__((ext_vector_type(8))) _Float16 f16x8;
typedef __attribute__((ext_vector_type(4))) _Float16 f16x4;
typedef __attribute__((ext_vector_type(4))) float f32x4;

#define NB 4
#define NS 4096
#define NE 512

__device__ __forceinline__ f16x8 cvt2(float4 a, float4 b) {
    f16x8 r;
    r[0] = (_Float16)a.x; r[1] = (_Float16)a.y; r[2] = (_Float16)a.z; r[3] = (_Float16)a.w;
    r[4] = (_Float16)b.x; r[5] = (_Float16)b.y; r[6] = (_Float16)b.z; r[7] = (_Float16)b.w;
    return r;
}
__device__ __forceinline__ void gload_lds16(const void* g, void* l) {
    __builtin_amdgcn_global_load_lds(
        (const __attribute__((address_space(1))) void*)g,
        (__attribute__((address_space(3))) void*)l, 16, 0, 0);
}

// ---------------- Stage 1: fused QKV projection (fp32 in, f16 out) ------
// q: natural [row][e]. k: swizzled rows — element (s,e) at s*512 + ((e/8)^(s&7))*8 + e%8.
// v: 32-key chunks with XOR chunk swizzle:
//    element (s,d) at ((bat*128 + ((s&4095)>>5))*512 + d)*32
//                    + ((((s&31)>>3) ^ ((d>>1)&3))<<3) + (s&7)
__global__ __launch_bounds__(256) void proj_kernel(
    const float* __restrict__ Xq, const float* __restrict__ Xk,
    const float* __restrict__ Xv,
    const float* __restrict__ Wq, const float* __restrict__ Wk,
    const float* __restrict__ Wv,
    const float* __restrict__ bq, const float* __restrict__ bk,
    const float* __restrict__ bv,
    _Float16* __restrict__ oq, _Float16* __restrict__ ok,
    _Float16* __restrict__ ovt, int b0)
{
    __shared__ __align__(16) _Float16 As[128 * 32];
    __shared__ __align__(16) _Float16 Bs[128 * 32];
    const int t = threadIdx.x;
    const int w = t >> 6, ln = t & 63;
    const int which = blockIdx.y;
    const float* X    = (which == 0) ? Xq : ((which == 1) ? Xk : Xv);
    const float* W    = (which == 0) ? Wq : ((which == 1) ? Wk : Wv);
    const float* bias = (which == 0) ? bq : ((which == 1) ? bk : bv);

    const int m0 = (blockIdx.x >> 2) * 128;
    const int n0 = (blockIdx.x & 3) * 128;

    const int srow  = t >> 1;
    const int shalf = (t & 1) * 16;
    const float* gA = X + ((size_t)b0 * NS + m0 + srow) * NE + shalf;
    const float* gB = W + (size_t)(n0 + srow) * NE + shalf;
    _Float16* lA = &As[srow * 32 + shalf];
    _Float16* lB = &Bs[srow * 32 + shalf];

    f32x4 acc[4][4] = {};
    const int wm = (w >> 1) * 64, wn = (w & 1) * 64;
    const int lcol = ln & 15, lq = ln >> 4;

    for (int k0 = 0; k0 < NE; k0 += 32) {
        float4 xa0 = *(const float4*)(gA + k0);
        float4 xa1 = *(const float4*)(gA + k0 + 4);
        float4 xa2 = *(const float4*)(gA + k0 + 8);
        float4 xa3 = *(const float4*)(gA + k0 + 12);
        float4 xb0 = *(const float4*)(gB + k0);
        float4 xb1 = *(const float4*)(gB + k0 + 4);
        float4 xb2 = *(const float4*)(gB + k0 + 8);
        float4 xb3 = *(const float4*)(gB + k0 + 12);
        __syncthreads();
        *(f16x8*)lA       = cvt2(xa0, xa1);
        *(f16x8*)(lA + 8) = cvt2(xa2, xa3);
        *(f16x8*)lB       = cvt2(xb0, xb1);
        *(f16x8*)(lB + 8) = cvt2(xb2, xb3);
        __syncthreads();
        f16x8 a[4], b[4];
#pragma unroll
        for (int i = 0; i < 4; i++)
            a[i] = *(const f16x8*)&As[(wm + i * 16 + lcol) * 32 + lq * 8];
#pragma unroll
        for (int j = 0; j < 4; j++)
            b[j] = *(const f16x8*)&Bs[(wn + j * 16 + lcol) * 32 + lq * 8];
#pragma unroll
        for (int i = 0; i < 4; i++)
#pragma unroll
            for (int j = 0; j < 4; j++)
                acc[i][j] = __builtin_amdgcn_mfma_f32_16x16x32_f16(a[i], b[j], acc[i][j], 0, 0, 0);
    }

    // C/D layout: col = lane&15, row = (lane>>4)*4 + reg
    if (which == 0) {
#pragma unroll
        for (int j = 0; j < 4; j++) {
            const int col = n0 + wn + j * 16 + lcol;
            const float bb = bias[col];
#pragma unroll
            for (int i = 0; i < 4; i++) {
                const int rbase = m0 + wm + i * 16 + lq * 4;
#pragma unroll
                for (int r = 0; r < 4; r++)
                    oq[(size_t)(rbase + r) * NE + col] = (_Float16)(acc[i][j][r] + bb);
            }
        }
    } else if (which == 1) {
#pragma unroll
        for (int j = 0; j < 4; j++) {
            const int col = n0 + wn + j * 16 + lcol;
            const int cch = col >> 3, clo = col & 7;
            const float bb = bias[col];
#pragma unroll
            for (int i = 0; i < 4; i++) {
                const int rbase = m0 + wm + i * 16 + lq * 4;
#pragma unroll
                for (int r = 0; r < 4; r++) {
                    const int s = rbase + r;
                    ok[(size_t)s * NE + ((cch ^ (s & 7)) << 3) + clo] =
                        (_Float16)(acc[i][j][r] + bb);
                }
            }
        }
    } else {
#pragma unroll
        for (int j = 0; j < 4; j++) {
            const int d = n0 + wn + j * 16 + lcol;
            const int dsw = (d >> 1) & 3;
            const float bb = bias[d];
#pragma unroll
            for (int i = 0; i < 4; i++) {
                const int rbase = m0 + wm + i * 16 + lq * 4;
                const int bat = rbase >> 12;
                const int sl  = rbase & 4095;
                const int ch  = ((sl >> 3) & 3) ^ dsw;
                f16x4 pk;
#pragma unroll
                for (int r = 0; r < 4; r++) pk[r] = (_Float16)(acc[i][j][r] + bb);
                *(f16x4*)&ovt[(((size_t)bat * 128 + (sl >> 5)) * NE + d) * 32
                              + (ch << 3) + (sl & 7)] = pk;
            }
        }
    }
}

// ---------------- Stage 2: flash attention v9 (specialized waves) -------
// 512 thr = 8 waves, 1 block/CU, 64 q-rows, KB=32 keys/iter, 128 iters' worth
// of keys in 64 loop iters... (4096/32 = 128? No: kc 0..127) — see loop bound.
// Waves 0-3 (producer): wave (qh=w&1, kh=w>>1): QK for rows qh*32..+32 x keys
//   kh*16..+16 of tile t, wave-local softmax, write P/m/l partials.
// Waves 4-7 (consumer): wave (qh, eh): rescale O + PV for tile t-1 using
//   Pb/mpart/Vb of t-1 — runs CONCURRENTLY with producer between the same
//   barriers (skewed pipeline). Everything double-buffered; 2 barriers/iter;
//   stages issued a full iteration ahead; counted vmcnt, no drain in loop.
#define NKC (NS / 32)
__global__ __launch_bounds__(512, 2) void attn_kernel(
    const _Float16* __restrict__ q, const _Float16* __restrict__ ksw,
    const _Float16* __restrict__ vsw, float* __restrict__ out, int b0)
{
    __shared__ __align__(16) _Float16 Kb[2][32 * 512];
    __shared__ __align__(16) _Float16 Vb[2][512 * 32];
    __shared__ __align__(16) _Float16 Pb[2][64 * 40];
    __shared__ float mpart[2][2][64];
    __shared__ float lpart[2][2][64];

    const int t = threadIdx.x, w = t >> 6, ln = t & 63;
    const int lcol = ln & 15, lq = ln >> 4;
    const int xm = lcol & 7;

    // XCD-aware swizzle (proven: FETCH 139->41 MB): 2 XCDs per batch
    int qx, rel;
    if (gridDim.y == 4) {
        const int id = blockIdx.x + (blockIdx.y << 6);   // 0..255, hw xcd = id&7
        const int xcd = id & 7, slot = id >> 3;          // slot 0..31
        rel = xcd >> 1;
        qx  = ((xcd & 1) << 5) + slot;
    } else { qx = blockIdx.x; rel = blockIdx.y; }
    const int babs = b0 + rel;
    const int q0 = qx * 64;

    const _Float16* kbase = ksw + (size_t)rel * NS * NE;
    const _Float16* vbase = vsw + (size_t)rel * NS * NE;

    auto stageK = [&](int kc, int pp) {
        const _Float16* src = kbase + (size_t)kc * 32 * NE;
#pragma unroll
        for (int i = 0; i < 4; i++) {
            const int blk = i * 8 + w;                   // 1 KB block index
            gload_lds16(src + blk * 512 + ln * 8, &Kb[pp][blk * 512]);
        }
    };
    auto stageV = [&](int kc, int pp) {
        const _Float16* src = vbase + (size_t)kc * NE * 32;
#pragma unroll
        for (int i = 0; i < 4; i++) {
            const int blk = i * 8 + w;
            gload_lds16(src + blk * 512 + ln * 8, &Vb[pp][blk * 512]);
        }
    };

    if (w < 4) {
        // ================= producer: QK + softmax =================
        const int qh = w & 1, kh = w >> 1;
        f16x8 qf[2][16];
        const _Float16* qp = q + ((size_t)rel * NS + q0 + qh * 32 + lcol) * NE + lq * 8;
#pragma unroll
        for (int qt = 0; qt < 2; qt++)
#pragma unroll
            for (int ks = 0; ks < 16; ks++)
                qf[qt][ks] = *(const f16x8*)(qp + qt * 16 * NE + ks * 32);
        asm volatile("" ::: "memory");
        stageK(0, 0);

        float m_st[2][4] = {{-1e30f, -1e30f, -1e30f, -1e30f},
                            {-1e30f, -1e30f, -1e30f, -1e30f}};
        for (int kc = 0; kc < NKC; kc++) {
            const int p = kc & 1;
            if (kc < NKC - 1) stageK(kc + 1, p ^ 1);
            stageV(kc, p);
            if (kc < NKC - 1) { asm volatile("s_waitcnt vmcnt(8)" ::: "memory"); }
            else              { asm volatile("s_waitcnt vmcnt(4)" ::: "memory"); }
            __builtin_amdgcn_s_barrier();                // B1: K(t), V(t-1) ready

            f32x4 sq[2] = {};
            __builtin_amdgcn_s_setprio(1);
#pragma unroll
            for (int ks = 0; ks < 16; ks++) {
                f16x8 kb = *(const f16x8*)&Kb[p][(kh * 16 + lcol) * 512 + ((ks * 4 + lq) ^ xm) * 8];
                sq[0] = __builtin_amdgcn_mfma_f32_16x16x32_f16(qf[0][ks], kb, sq[0], 0, 0, 0);
                sq[1] = __builtin_amdgcn_mfma_f32_16x16x32_f16(qf[1][ks], kb, sq[1], 0, 0, 0);
            }
            __builtin_amdgcn_s_setprio(0);

            float Mg[2][4];
#pragma unroll
            for (int qt = 0; qt < 2; qt++) {
#pragma unroll
                for (int r = 0; r < 4; r++) {
                    float mx = sq[qt][r];
#pragma unroll
                    for (int msk = 8; msk; msk >>= 1) mx = fmaxf(mx, __shfl_xor(mx, msk, 64));
                    const float mg = fmaxf(m_st[qt][r], mx);
                    const float pe = __expf(sq[qt][r] - mg);
                    const int row = qh * 32 + qt * 16 + lq * 4 + r;
                    Pb[p][row * 40 + kh * 16 + lcol] = (_Float16)pe;
                    float ls = pe;
#pragma unroll
                    for (int msk = 8; msk; msk >>= 1) ls += __shfl_xor(ls, msk, 64);
                    if (lcol == 0) {
                        mpart[p][kh][row] = mg;
                        lpart[p][kh][row] = ls;
                    }
                    Mg[qt][r] = mg;
                }
            }
            asm volatile("s_waitcnt lgkmcnt(0)" ::: "memory");
            __builtin_amdgcn_s_barrier();                // B2: P/partials visible
            // fold the other kh half into the running max
#pragma unroll
            for (int qt = 0; qt < 2; qt++)
#pragma unroll
                for (int r = 0; r < 4; r++) {
                    const int row = qh * 32 + qt * 16 + lq * 4 + r;
                    m_st[qt][r] = fmaxf(Mg[qt][r], mpart[p][kh ^ 1][row]);
                }
        }
        asm volatile("s_waitcnt vmcnt(0)" ::: "memory");
        __builtin_amdgcn_s_barrier();                    // epilogue barrier
    } else {
        // ================= consumer: rescale + PV =================
        const int qh = w & 1, eh = (w >> 1) & 1;
        stageK(0, 0);
        f32x4 oacc[2][16] = {};
        float m_st[2][4] = {{-1e30f, -1e30f, -1e30f, -1e30f},
                            {-1e30f, -1e30f, -1e30f, -1e30f}};
        float l_st[2][4] = {};

        auto pvphase = [&](int pp) {
            float alpha[2][4];
            bool allone = true;
#pragma unroll
            for (int qt = 0; qt < 2; qt++)
#pragma unroll
                for (int r = 0; r < 4; r++) {
                    const int row = qh * 32 + qt * 16 + lq * 4 + r;
                    const float M0 = mpart[pp][0][row], M1 = mpart[pp][1][row];
                    const float mn = fmaxf(M0, M1);
                    const float a = __expf(m_st[qt][r] - mn);
                    l_st[qt][r] = l_st[qt][r] * a
                                + __expf(M0 - mn) * lpart[pp][0][row]
                                + __expf(M1 - mn) * lpart[pp][1][row];
                    m_st[qt][r] = mn;
                    alpha[qt][r] = a;
                    allone = allone & (a == 1.f);
                }
            if (!__all(allone)) {
#pragma unroll
                for (int qt = 0; qt < 2; qt++)
#pragma unroll
                    for (int et = 0; et < 16; et++) {
                        oacc[qt][et][0] *= alpha[qt][0];
                        oacc[qt][et][1] *= alpha[qt][1];
                        oacc[qt][et][2] *= alpha[qt][2];
                        oacc[qt][et][3] *= alpha[qt][3];
                    }
            }
            f16x8 pa[2];
#pragma unroll
            for (int qt = 0; qt < 2; qt++) {
                const int frow = qh * 32 + qt * 16 + lcol;
                const float F0 = mpart[pp][0][frow], F1 = mpart[pp][1][frow];
                const float fm = fmaxf(F0, F1);
                const _Float16 cf = (_Float16)__expf((((lq >> 1) == 0) ? F0 : F1) - fm);
                pa[qt] = *(const f16x8*)&Pb[pp][frow * 40 + lq * 8];
#pragma unroll
                for (int j = 0; j < 8; j++) pa[qt][j] *= cf;
            }
            __builtin_amdgcn_s_setprio(1);
#pragma unroll
            for (int et = 0; et < 16; et++) {
                const int e = eh * 256 + et * 16 + lcol;
                f16x8 vf = *(const f16x8*)&Vb[pp][e * 32 + ((lq ^ ((e >> 1) & 3)) * 8)];
                oacc[0][et] = __builtin_amdgcn_mfma_f32_16x16x32_f16(pa[0], vf, oacc[0][et], 0, 0, 0);
                oacc[1][et] = __builtin_amdgcn_mfma_f32_16x16x32_f16(pa[1], vf, oacc[1][et], 0, 0, 0);
            }
            __builtin_amdgcn_s_setprio(0);
        };

        for (int kc = 0; kc < NKC; kc++) {
            const int p = kc & 1;
            if (kc < NKC - 1) stageK(kc + 1, p ^ 1);
            stageV(kc, p);
            if (kc < NKC - 1) { asm volatile("s_waitcnt vmcnt(8)" ::: "memory"); }
            else              { asm volatile("s_waitcnt vmcnt(4)" ::: "memory"); }
            __builtin_amdgcn_s_barrier();                // B1
            if (kc > 0) pvphase(p ^ 1);                  // PV on tile t-1
            __builtin_amdgcn_s_barrier();                // B2
        }
        asm volatile("s_waitcnt vmcnt(0)" ::: "memory");
        __builtin_amdgcn_s_barrier();                    // epilogue barrier
        pvphase((NKC - 1) & 1);                          // final tile

#pragma unroll
        for (int qt = 0; qt < 2; qt++)
#pragma unroll
            for (int r = 0; r < 4; r++) {
                const float inv = 1.0f / l_st[qt][r];
                const size_t ob = ((size_t)babs * NS + q0 + qh * 32 + qt * 16 + lq * 4 + r) * NE
                                + eh * 256 + lcol;
#pragma unroll
                for (int et = 0; et < 16; et++)
                    out[ob + et * 16] = oacc[qt][et][r] * inv;
            }
    }
}

extern "C" void kernel_launch(void* const* d_in, const int* in_sizes, int n_in,
                              void* d_out, int out_size, void* d_ws, size_t ws_size,
                              hipStream_t stream) {
    const float* query = (const float*)d_in[0];
    const float* key_  = (const float*)d_in[1];
    const float* value = (const float*)d_in[2];
    const float* Wq    = (const float*)d_in[3];
    const float* bq    = (const float*)d_in[4];
    const float* Wk    = (const float*)d_in[5];
    const float* bk    = (const float*)d_in[6];
    const float* Wv    = (const float*)d_in[7];
    const float* bv    = (const float*)d_in[8];

    const size_t per_batch = (size_t)3 * NS * NE * 2;   // q + k_sw + v_sw f16 = 12 MiB
    int nb_chunk = (int)(ws_size / per_batch);
    if (nb_chunk > NB) nb_chunk = NB;
    if (nb_chunk < 1)  nb_chunk = 1;

    _Float16* qh  = (_Float16*)d_ws;
    _Float16* kh  = qh + (size_t)nb_chunk * NS * NE;
    _Float16* vth = kh + (size_t)nb_chunk * NS * NE;

    for (int b0 = 0; b0 < NB; b0 += nb_chunk) {
        int nb = NB - b0 < nb_chunk ? NB - b0 : nb_chunk;
        proj_kernel<<<dim3(nb * 128, 3, 1), 256, 0, stream>>>(
            query, key_, value, Wq, Wk, Wv, bq, bk, bv, qh, kh, vth, b0);
        attn_kernel<<<dim3(NS / 64, nb, 1), 512, 0, stream>>>(
            qh, kh, vth, (float*)d_out, b0);
    }
}

// Round 6
// 452.581 us; speedup vs baseline: 1.4162x; 1.4162x over previous
//
#include <hip/hip_runtime.h>

typedef __attribute__((ext_vector_type(8))) _Float16 f16x8;
typedef __attribute__((ext_vector_type(4))) _Float16 f16x4;
typedef __attribute__((ext_vector_type(4))) float f32x4;

#define NB 4
#define NS 4096
#define NE 512

__device__ __forceinline__ f16x8 cvt2(float4 a, float4 b) {
    f16x8 r;
    r[0] = (_Float16)a.x; r[1] = (_Float16)a.y; r[2] = (_Float16)a.z; r[3] = (_Float16)a.w;
    r[4] = (_Float16)b.x; r[5] = (_Float16)b.y; r[6] = (_Float16)b.z; r[7] = (_Float16)b.w;
    return r;
}
__device__ __forceinline__ void gload_lds16(const void* g, void* l) {
    __builtin_amdgcn_global_load_lds(
        (const __attribute__((address_space(1))) void*)g,
        (__attribute__((address_space(3))) void*)l, 16, 0, 0);
}

// DPP ring reductions over the 16-lane row (pure VALU, no DS latency).
// dpp_ctrl must be a compile-time constant -> template parameter.
template <int CTRL>
__device__ __forceinline__ float dpp_ror(float x) {
    int r = __builtin_amdgcn_update_dpp(
        0, __builtin_bit_cast(int, x), CTRL, 0xF, 0xF, true);
    return __builtin_bit_cast(float, r);
}
__device__ __forceinline__ float rmax16(float x) {
    x = fmaxf(x, dpp_ror<0x128>(x));   // row_ror:8
    x = fmaxf(x, dpp_ror<0x124>(x));   // row_ror:4
    x = fmaxf(x, dpp_ror<0x122>(x));   // row_ror:2
    x = fmaxf(x, dpp_ror<0x121>(x));   // row_ror:1
    return x;
}
__device__ __forceinline__ float rsum16(float x) {
    x += dpp_ror<0x128>(x);
    x += dpp_ror<0x124>(x);
    x += dpp_ror<0x122>(x);
    x += dpp_ror<0x121>(x);
    return x;
}

// ---------------- Stage 1: fused QKV projection (fp32 in, f16 out) ------
// q: natural [row][e]. k: swizzled rows — element (s,e) at s*512 + ((e/8)^(s&7))*8 + e%8.
// v: chunked+swizzled [b][kc][e][64]: (d,s) at ((b*64+kc)*512+d)*64 + (((s&63)/8)^(d&7))*8 + s%8.
__global__ __launch_bounds__(256) void proj_kernel(
    const float* __restrict__ Xq, const float* __restrict__ Xk,
    const float* __restrict__ Xv,
    const float* __restrict__ Wq, const float* __restrict__ Wk,
    const float* __restrict__ Wv,
    const float* __restrict__ bq, const float* __restrict__ bk,
    const float* __restrict__ bv,
    _Float16* __restrict__ oq, _Float16* __restrict__ ok,
    _Float16* __restrict__ ovt, int b0)
{
    __shared__ __align__(16) _Float16 As[128 * 32];
    __shared__ __align__(16) _Float16 Bs[128 * 32];
    const int t = threadIdx.x;
    const int w = t >> 6, ln = t & 63;
    const int which = blockIdx.y;
    const float* X    = (which == 0) ? Xq : ((which == 1) ? Xk : Xv);
    const float* W    = (which == 0) ? Wq : ((which == 1) ? Wk : Wv);
    const float* bias = (which == 0) ? bq : ((which == 1) ? bk : bv);

    const int m0 = (blockIdx.x >> 2) * 128;
    const int n0 = (blockIdx.x & 3) * 128;

    const int srow  = t >> 1;
    const int shalf = (t & 1) * 16;
    const float* gA = X + ((size_t)b0 * NS + m0 + srow) * NE + shalf;
    const float* gB = W + (size_t)(n0 + srow) * NE + shalf;
    _Float16* lA = &As[srow * 32 + shalf];
    _Float16* lB = &Bs[srow * 32 + shalf];

    f32x4 acc[4][4] = {};
    const int wm = (w >> 1) * 64, wn = (w & 1) * 64;
    const int lcol = ln & 15, lq = ln >> 4;

    for (int k0 = 0; k0 < NE; k0 += 32) {
        float4 xa0 = *(const float4*)(gA + k0);
        float4 xa1 = *(const float4*)(gA + k0 + 4);
        float4 xa2 = *(const float4*)(gA + k0 + 8);
        float4 xa3 = *(const float4*)(gA + k0 + 12);
        float4 xb0 = *(const float4*)(gB + k0);
        float4 xb1 = *(const float4*)(gB + k0 + 4);
        float4 xb2 = *(const float4*)(gB + k0 + 8);
        float4 xb3 = *(const float4*)(gB + k0 + 12);
        __syncthreads();
        *(f16x8*)lA       = cvt2(xa0, xa1);
        *(f16x8*)(lA + 8) = cvt2(xa2, xa3);
        *(f16x8*)lB       = cvt2(xb0, xb1);
        *(f16x8*)(lB + 8) = cvt2(xb2, xb3);
        __syncthreads();
        f16x8 a[4], b[4];
#pragma unroll
        for (int i = 0; i < 4; i++)
            a[i] = *(const f16x8*)&As[(wm + i * 16 + lcol) * 32 + lq * 8];
#pragma unroll
        for (int j = 0; j < 4; j++)
            b[j] = *(const f16x8*)&Bs[(wn + j * 16 + lcol) * 32 + lq * 8];
#pragma unroll
        for (int i = 0; i < 4; i++)
#pragma unroll
            for (int j = 0; j < 4; j++)
                acc[i][j] = __builtin_amdgcn_mfma_f32_16x16x32_f16(a[i], b[j], acc[i][j], 0, 0, 0);
    }

    // C/D layout: col = lane&15, row = (lane>>4)*4 + reg
    if (which == 0) {
#pragma unroll
        for (int j = 0; j < 4; j++) {
            const int col = n0 + wn + j * 16 + lcol;
            const float bb = bias[col];
#pragma unroll
            for (int i = 0; i < 4; i++) {
                const int rbase = m0 + wm + i * 16 + lq * 4;
#pragma unroll
                for (int r = 0; r < 4; r++)
                    oq[(size_t)(rbase + r) * NE + col] = (_Float16)(acc[i][j][r] + bb);
            }
        }
    } else if (which == 1) {
#pragma unroll
        for (int j = 0; j < 4; j++) {
            const int col = n0 + wn + j * 16 + lcol;
            const int cch = col >> 3, clo = col & 7;
            const float bb = bias[col];
#pragma unroll
            for (int i = 0; i < 4; i++) {
                const int rbase = m0 + wm + i * 16 + lq * 4;
#pragma unroll
                for (int r = 0; r < 4; r++) {
                    const int s = rbase + r;
                    ok[(size_t)s * NE + ((cch ^ (s & 7)) << 3) + clo] =
                        (_Float16)(acc[i][j][r] + bb);
                }
            }
        }
    } else {
#pragma unroll
        for (int j = 0; j < 4; j++) {
            const int d = n0 + wn + j * 16 + lcol;
            const float bb = bias[d];
#pragma unroll
            for (int i = 0; i < 4; i++) {
                const int rbase = m0 + wm + i * 16 + lq * 4;
                const int bat = rbase >> 12;
                const int sl  = rbase & 4095;
                const int kc  = sl >> 6;
                const int slot = ((sl >> 3) & 7) ^ (d & 7);
                f16x4 pk;
#pragma unroll
                for (int r = 0; r < 4; r++) pk[r] = (_Float16)(acc[i][j][r] + bb);
                *(f16x4*)&ovt[(((size_t)bat * 64 + kc) * NE + d) * 64 + slot * 8 + (sl & 7)] = pk;
            }
        }
    }
}

// ---------------- Stage 2: flash attention v10 --------------------------
// v5 skeleton (KB=64, 8 waves, 64 iters, 1 block/CU) with the serial chain
// removed: (1) split K/V staging in single buffers with counted vmcnt(8)
// (stage issued a phase ahead, proven in v8); (2) DPP ring reductions for
// softmax (VALU, no ds_swizzle latency); (3) folded-max softmax — P written
// with wave-local max, per-half correction exp(Mg-mn) on the A-fragment
// (proven in v6). 4 barriers/iter, no in-loop vmcnt(0) drain.
// wave w: rt=w&3 (16 q-rows); g=w>>2: QK keys [g*32,+32), PV E [g*256,+256).
__global__ __launch_bounds__(512, 2) void attn_kernel(
    const _Float16* __restrict__ q, const _Float16* __restrict__ ksw,
    const _Float16* __restrict__ vsw, float* __restrict__ out, int b0)
{
    __shared__ __align__(16) _Float16 Kb[64 * 512];
    __shared__ __align__(16) _Float16 Vb[512 * 64];
    __shared__ __align__(16) _Float16 Pb[64 * 72];
    __shared__ float mpart[2][64];
    __shared__ float lpart[2][64];

    const int t = threadIdx.x, w = t >> 6, ln = t & 63;
    const int lcol = ln & 15, lq = ln >> 4;
    const int rt = w & 3, g = w >> 2;
    const int xm = lcol & 7;

    // XCD-aware swizzle (proven: FETCH 139->41 MB): 2 XCDs per batch
    int qx, rel;
    if (gridDim.y == 4) {
        const int id = blockIdx.x + (blockIdx.y << 6);   // 0..255, hw xcd = id&7
        const int xcd = id & 7, slot = id >> 3;          // slot 0..31
        rel = xcd >> 1;
        qx  = ((xcd & 1) << 5) + slot;
    } else { qx = blockIdx.x; rel = blockIdx.y; }
    const int babs = b0 + rel;
    const int q0 = qx * 64;

    const _Float16* qp = q + ((size_t)rel * NS + q0 + rt * 16 + lcol) * NE + lq * 8;
    f16x8 qf[16];
#pragma unroll
    for (int ks = 0; ks < 16; ks++) qf[ks] = *(const f16x8*)(qp + ks * 32);

    const _Float16* kbase = ksw + (size_t)rel * NS * NE;
    const _Float16* vbase = vsw + (size_t)rel * NS * NE;

    auto stageK = [&](int kc) {
        const _Float16* src = kbase + (size_t)kc * 64 * NE;
#pragma unroll
        for (int i = 0; i < 8; i++) {
            const int blk = i * 8 + w;                   // 1 KB block index
            gload_lds16(src + (size_t)blk * 512 + ln * 8, (_Float16*)Kb + blk * 512);
        }
    };
    auto stageV = [&](int kc) {
        const _Float16* src = vbase + (size_t)kc * NE * 64;
#pragma unroll
        for (int i = 0; i < 8; i++) {
            const int blk = i * 8 + w;
            gload_lds16(src + (size_t)blk * 512 + ln * 8, (_Float16*)Vb + blk * 512);
        }
    };

    f32x4 oacc[16] = {};
    float m_st[4] = {-1e30f, -1e30f, -1e30f, -1e30f};
    float l_st[4] = {0.f, 0.f, 0.f, 0.f};

    asm volatile("" ::: "memory");
    stageK(0);
    stageV(0);

    for (int kc = 0; kc < 64; kc++) {
        // K(t) done (V(t) / K(t+1) stay in flight); then cross-wave sync
        asm volatile("s_waitcnt vmcnt(8)" ::: "memory");
        __builtin_amdgcn_s_barrier();                    // A: K(t) visible
        asm volatile("" ::: "memory");

        // ---- QK^T: 16 q-rows x 32 keys (keys g*32..+32), K=512
        f32x4 s0 = {}, s1 = {};
        __builtin_amdgcn_s_setprio(1);
#pragma unroll
        for (int ks = 0; ks < 16; ks++) {
            const int ch = ((ks * 4 + lq) ^ xm) * 8;
            f16x8 kb0 = *(const f16x8*)&Kb[(g * 32 + lcol) * 512 + ch];
            f16x8 kb1 = *(const f16x8*)&Kb[(g * 32 + 16 + lcol) * 512 + ch];
            s0 = __builtin_amdgcn_mfma_f32_16x16x32_f16(qf[ks], kb0, s0, 0, 0, 0);
            s1 = __builtin_amdgcn_mfma_f32_16x16x32_f16(qf[ks], kb1, s1, 0, 0, 0);
        }
        __builtin_amdgcn_s_setprio(0);

        asm volatile("" ::: "memory");
        __builtin_amdgcn_s_barrier();                    // B: Kb free
        asm volatile("" ::: "memory");
        if (kc < 63) stageK(kc + 1);                     // overlaps softmax+PV

        // ---- wave-local folded softmax (rows lq*4+r, keys g*32 + {lcol,16+lcol})
        float Mg[4];
#pragma unroll
        for (int r = 0; r < 4; r++) {
            float mx = rmax16(fmaxf(s0[r], s1[r]));
            Mg[r] = fmaxf(m_st[r], mx);
            const float p0 = __expf(s0[r] - Mg[r]);
            const float p1 = __expf(s1[r] - Mg[r]);
            const int row = rt * 16 + lq * 4 + r;
            Pb[row * 72 + g * 32 + lcol]      = (_Float16)p0;
            Pb[row * 72 + g * 32 + 16 + lcol] = (_Float16)p1;
            const float ls = rsum16(p0 + p1);
            if (lcol == 0) { mpart[g][row] = Mg[r]; lpart[g][row] = ls; }
        }

        // V(t) done + own P/partial writes visible; then sync
        if (kc < 63) { asm volatile("s_waitcnt vmcnt(8) lgkmcnt(0)" ::: "memory"); }
        else         { asm volatile("s_waitcnt vmcnt(0) lgkmcnt(0)" ::: "memory"); }
        __builtin_amdgcn_s_barrier();                    // C: V(t), P, partials
        asm volatile("" ::: "memory");

        // ---- combine halves; update running state (state rows lq*4+r)
        float alpha[4];
#pragma unroll
        for (int r = 0; r < 4; r++) {
            const int row = rt * 16 + lq * 4 + r;
            const float M0 = mpart[0][row], M1 = mpart[1][row];
            const float mn = fmaxf(M0, M1);
            alpha[r] = __expf(m_st[r] - mn);
            l_st[r] = l_st[r] * alpha[r]
                    + __expf(M0 - mn) * lpart[0][row]
                    + __expf(M1 - mn) * lpart[1][row];
            m_st[r] = mn;
        }
        const bool allone = (alpha[0] == 1.f) & (alpha[1] == 1.f) &
                            (alpha[2] == 1.f) & (alpha[3] == 1.f);
        if (!__all(allone)) {
#pragma unroll
            for (int et = 0; et < 16; et++) {
                oacc[et][0] *= alpha[0]; oacc[et][1] *= alpha[1];
                oacc[et][2] *= alpha[2]; oacc[et][3] *= alpha[3];
            }
        }

        // ---- P A-fragment (rows = lcol): per-half correction exp(Mg - mn)
        // pa0 = keys 0..31 (written by g=0 wave), pa1 = keys 32..63 (g=1)
        const int frow = rt * 16 + lcol;
        const float F0 = mpart[0][frow], F1 = mpart[1][frow];
        const float fm = fmaxf(F0, F1);
        const _Float16 c0 = (_Float16)__expf(F0 - fm);
        const _Float16 c1 = (_Float16)__expf(F1 - fm);
        f16x8 pa0 = *(const f16x8*)&Pb[frow * 72 + lq * 8];
        f16x8 pa1 = *(const f16x8*)&Pb[frow * 72 + 32 + lq * 8];
#pragma unroll
        for (int j = 0; j < 8; j++) { pa0[j] *= c0; pa1[j] *= c1; }

        // ---- PV: rows rt*16..+16, E-cols g*256..+256, K=64
        __builtin_amdgcn_s_setprio(1);
#pragma unroll
        for (int et = 0; et < 16; et++) {
            const int e = g * 256 + et * 16 + lcol;
            f16x8 v0 = *(const f16x8*)&Vb[e * 64 + ((lq ^ xm) * 8)];
            f16x8 v1 = *(const f16x8*)&Vb[e * 64 + (((4 + lq) ^ xm) * 8)];
            oacc[et] = __builtin_amdgcn_mfma_f32_16x16x32_f16(pa0, v0, oacc[et], 0, 0, 0);
            oacc[et] = __builtin_amdgcn_mfma_f32_16x16x32_f16(pa1, v1, oacc[et], 0, 0, 0);
        }
        __builtin_amdgcn_s_setprio(0);

        asm volatile("" ::: "memory");
        __builtin_amdgcn_s_barrier();                    // D: Vb free
        asm volatile("" ::: "memory");
        if (kc < 63) stageV(kc + 1);                     // overlaps next QK
    }

#pragma unroll
    for (int r = 0; r < 4; r++) {
        const float inv = 1.0f / l_st[r];
        const size_t ob = ((size_t)babs * NS + q0 + rt * 16 + lq * 4 + r) * NE + g * 256 + lcol;
#pragma unroll
        for (int et = 0; et < 16; et++)
            out[ob + et * 16] = oacc[et][r] * inv;
    }
}

extern "C" void kernel_launch(void* const* d_in, const int* in_sizes, int n_in,
                              void* d_out, int out_size, void* d_ws, size_t ws_size,
                              hipStream_t stream) {
    const float* query = (const float*)d_in[0];
    const float* key_  = (const float*)d_in[1];
    const float* value = (const float*)d_in[2];
    const float* Wq    = (const float*)d_in[3];
    const float* bq    = (const float*)d_in[4];
    const float* Wk    = (const float*)d_in[5];
    const float* bk    = (const float*)d_in[6];
    const float* Wv    = (const float*)d_in[7];
    const float* bv    = (const float*)d_in[8];

    const size_t per_batch = (size_t)3 * NS * NE * 2;   // q + k_sw + v_sw f16 = 12 MiB
    int nb_chunk = (int)(ws_size / per_batch);
    if (nb_chunk > NB) nb_chunk = NB;
    if (nb_chunk < 1)  nb_chunk = 1;

    _Float16* qh  = (_Float16*)d_ws;
    _Float16* kh  = qh + (size_t)nb_chunk * NS * NE;
    _Float16* vth = kh + (size_t)nb_chunk * NS * NE;

    for (int b0 = 0; b0 < NB; b0 += nb_chunk) {
        int nb = NB - b0 < nb_chunk ? NB - b0 : nb_chunk;
        proj_kernel<<<dim3(nb * 128, 3, 1), 256, 0, stream>>>(
            query, key_, value, Wq, Wk, Wv, bq, bk, bv, qh, kh, vth, b0);
        attn_kernel<<<dim3(NS / 64, nb, 1), 512, 0, stream>>>(
            qh, kh, vth, (float*)d_out, b0);
    }
}

// Round 8
// 449.128 us; speedup vs baseline: 1.4271x; 1.0077x over previous
//
#include <hip/hip_runtime.h>

typedef __attribute__((ext_vector_type(8))) _Float16 f16x8;
typedef __attribute__((ext_vector_type(4))) _Float16 f16x4;
typedef __attribute__((ext_vector_type(4))) float f32x4;

#define NB 4
#define NS 4096
#define NE 512

__device__ __forceinline__ f16x8 cvt2(float4 a, float4 b) {
    f16x8 r;
    r[0] = (_Float16)a.x; r[1] = (_Float16)a.y; r[2] = (_Float16)a.z; r[3] = (_Float16)a.w;
    r[4] = (_Float16)b.x; r[5] = (_Float16)b.y; r[6] = (_Float16)b.z; r[7] = (_Float16)b.w;
    return r;
}
__device__ __forceinline__ void gload_lds16(const void* g, void* l) {
    __builtin_amdgcn_global_load_lds(
        (const __attribute__((address_space(1))) void*)g,
        (__attribute__((address_space(3))) void*)l, 16, 0, 0);
}

// DPP ring reductions over the 16-lane row (pure VALU, no DS latency).
template <int CTRL>
__device__ __forceinline__ float dpp_ror(float x) {
    int r = __builtin_amdgcn_update_dpp(
        0, __builtin_bit_cast(int, x), CTRL, 0xF, 0xF, true);
    return __builtin_bit_cast(float, r);
}
__device__ __forceinline__ float rmax16(float x) {
    x = fmaxf(x, dpp_ror<0x128>(x));   // row_ror:8
    x = fmaxf(x, dpp_ror<0x124>(x));   // row_ror:4
    x = fmaxf(x, dpp_ror<0x122>(x));   // row_ror:2
    x = fmaxf(x, dpp_ror<0x121>(x));   // row_ror:1
    return x;
}
__device__ __forceinline__ float rsum16(float x) {
    x += dpp_ror<0x128>(x);
    x += dpp_ror<0x124>(x);
    x += dpp_ror<0x122>(x);
    x += dpp_ror<0x121>(x);
    return x;
}

// ---------------- Stage 1: fused QKV projection (fp32 in, f16 out) ------
// v11: software-pipelined register staging — global loads for tile t+1
// issued right after the LDS writes of tile t, hiding L2/HBM latency under
// compute(t). Static ping-pong register sets (no runtime-indexed arrays).
// q: natural [row][e]. k: swizzled rows — element (s,e) at s*512 + ((e/8)^(s&7))*8 + e%8.
// v: chunked+swizzled [b][kc][e][64]: (d,s) at ((b*64+kc)*512+d)*64 + (((s&63)/8)^(d&7))*8 + s%8.
__global__ __launch_bounds__(256, 2) void proj_kernel(
    const float* __restrict__ Xq, const float* __restrict__ Xk,
    const float* __restrict__ Xv,
    const float* __restrict__ Wq, const float* __restrict__ Wk,
    const float* __restrict__ Wv,
    const float* __restrict__ bq, const float* __restrict__ bk,
    const float* __restrict__ bv,
    _Float16* __restrict__ oq, _Float16* __restrict__ ok,
    _Float16* __restrict__ ovt, int b0)
{
    __shared__ __align__(16) _Float16 As[128 * 32];
    __shared__ __align__(16) _Float16 Bs[128 * 32];
    const int t = threadIdx.x;
    const int w = t >> 6, ln = t & 63;
    const int which = blockIdx.y;
    const float* X    = (which == 0) ? Xq : ((which == 1) ? Xk : Xv);
    const float* W    = (which == 0) ? Wq : ((which == 1) ? Wk : Wv);
    const float* bias = (which == 0) ? bq : ((which == 1) ? bk : bv);

    const int m0 = (blockIdx.x >> 2) * 128;
    const int n0 = (blockIdx.x & 3) * 128;

    const int srow  = t >> 1;
    const int shalf = (t & 1) * 16;
    const float* gA = X + ((size_t)b0 * NS + m0 + srow) * NE + shalf;
    const float* gB = W + (size_t)(n0 + srow) * NE + shalf;
    _Float16* lA = &As[srow * 32 + shalf];
    _Float16* lB = &Bs[srow * 32 + shalf];

    f32x4 acc[4][4] = {};
    const int wm = (w >> 1) * 64, wn = (w & 1) * 64;
    const int lcol = ln & 15, lq = ln >> 4;

    float4 ra[4], rb[4], na[4], nb[4];

    auto LOAD = [&](int k0, float4* da, float4* db) {
        da[0] = *(const float4*)(gA + k0);
        da[1] = *(const float4*)(gA + k0 + 4);
        da[2] = *(const float4*)(gA + k0 + 8);
        da[3] = *(const float4*)(gA + k0 + 12);
        db[0] = *(const float4*)(gB + k0);
        db[1] = *(const float4*)(gB + k0 + 4);
        db[2] = *(const float4*)(gB + k0 + 8);
        db[3] = *(const float4*)(gB + k0 + 12);
    };
    auto WRITE = [&](const float4* da, const float4* db) {
        *(f16x8*)lA       = cvt2(da[0], da[1]);
        *(f16x8*)(lA + 8) = cvt2(da[2], da[3]);
        *(f16x8*)lB       = cvt2(db[0], db[1]);
        *(f16x8*)(lB + 8) = cvt2(db[2], db[3]);
    };
    auto COMPUTE = [&]() {
        f16x8 a[4], b[4];
#pragma unroll
        for (int i = 0; i < 4; i++)
            a[i] = *(const f16x8*)&As[(wm + i * 16 + lcol) * 32 + lq * 8];
#pragma unroll
        for (int j = 0; j < 4; j++)
            b[j] = *(const f16x8*)&Bs[(wn + j * 16 + lcol) * 32 + lq * 8];
#pragma unroll
        for (int i = 0; i < 4; i++)
#pragma unroll
            for (int j = 0; j < 4; j++)
                acc[i][j] = __builtin_amdgcn_mfma_f32_16x16x32_f16(a[i], b[j], acc[i][j], 0, 0, 0);
    };

    LOAD(0, ra, rb);
#pragma unroll
    for (int kk = 0; kk < 8; kk++) {
        // even phase: tile t = 2kk (regs ra/rb), prefetch t+1 into na/nb
        __syncthreads();                   // buf free (all read prev tile)
        WRITE(ra, rb);
        LOAD((2 * kk + 1) * 32, na, nb);   // overlaps compute below
        __syncthreads();                   // buf visible
        COMPUTE();
        // odd phase: tile t = 2kk+1 (regs na/nb), prefetch t+1 into ra/rb
        __syncthreads();
        WRITE(na, nb);
        if (kk < 7) LOAD((2 * kk + 2) * 32, ra, rb);
        __syncthreads();
        COMPUTE();
    }

    // C/D layout: col = lane&15, row = (lane>>4)*4 + reg
    if (which == 0) {
#pragma unroll
        for (int j = 0; j < 4; j++) {
            const int col = n0 + wn + j * 16 + lcol;
            const float bb = bias[col];
#pragma unroll
            for (int i = 0; i < 4; i++) {
                const int rbase = m0 + wm + i * 16 + lq * 4;
#pragma unroll
                for (int r = 0; r < 4; r++)
                    oq[(size_t)(rbase + r) * NE + col] = (_Float16)(acc[i][j][r] + bb);
            }
        }
    } else if (which == 1) {
#pragma unroll
        for (int j = 0; j < 4; j++) {
            const int col = n0 + wn + j * 16 + lcol;
            const int cch = col >> 3, clo = col & 7;
            const float bb = bias[col];
#pragma unroll
            for (int i = 0; i < 4; i++) {
                const int rbase = m0 + wm + i * 16 + lq * 4;
#pragma unroll
                for (int r = 0; r < 4; r++) {
                    const int s = rbase + r;
                    ok[(size_t)s * NE + ((cch ^ (s & 7)) << 3) + clo] =
                        (_Float16)(acc[i][j][r] + bb);
                }
            }
        }
    } else {
#pragma unroll
        for (int j = 0; j < 4; j++) {
            const int d = n0 + wn + j * 16 + lcol;
            const float bb = bias[d];
#pragma unroll
            for (int i = 0; i < 4; i++) {
                const int rbase = m0 + wm + i * 16 + lq * 4;
                const int bat = rbase >> 12;
                const int sl  = rbase & 4095;
                const int kc  = sl >> 6;
                const int slot = ((sl >> 3) & 7) ^ (d & 7);
                f16x4 pk;
#pragma unroll
                for (int r = 0; r < 4; r++) pk[r] = (_Float16)(acc[i][j][r] + bb);
                *(f16x4*)&ovt[(((size_t)bat * 64 + kc) * NE + d) * 64 + slot * 8 + (sl & 7)] = pk;
            }
        }
    }
}

// ---------------- Stage 2: flash attention v10 (unchanged) --------------
// v5 skeleton (KB=64, 8 waves, 64 iters, 1 block/CU) with the serial chain
// removed: (1) split K/V staging in single buffers with counted vmcnt(8);
// (2) DPP ring reductions; (3) folded-max softmax with per-half correction
// on the A-fragment. 4 barriers/iter, no in-loop vmcnt(0) drain.
// wave w: rt=w&3 (16 q-rows); g=w>>2: QK keys [g*32,+32), PV E [g*256,+256).
__global__ __launch_bounds__(512, 2) void attn_kernel(
    const _Float16* __restrict__ q, const _Float16* __restrict__ ksw,
    const _Float16* __restrict__ vsw, float* __restrict__ out, int b0)
{
    __shared__ __align__(16) _Float16 Kb[64 * 512];
    __shared__ __align__(16) _Float16 Vb[512 * 64];
    __shared__ __align__(16) _Float16 Pb[64 * 72];
    __shared__ float mpart[2][64];
    __shared__ float lpart[2][64];

    const int t = threadIdx.x, w = t >> 6, ln = t & 63;
    const int lcol = ln & 15, lq = ln >> 4;
    const int rt = w & 3, g = w >> 2;
    const int xm = lcol & 7;

    // XCD-aware swizzle (proven: FETCH 139->41 MB): 2 XCDs per batch
    int qx, rel;
    if (gridDim.y == 4) {
        const int id = blockIdx.x + (blockIdx.y << 6);   // 0..255, hw xcd = id&7
        const int xcd = id & 7, slot = id >> 3;          // slot 0..31
        rel = xcd >> 1;
        qx  = ((xcd & 1) << 5) + slot;
    } else { qx = blockIdx.x; rel = blockIdx.y; }
    const int babs = b0 + rel;
    const int q0 = qx * 64;

    const _Float16* qp = q + ((size_t)rel * NS + q0 + rt * 16 + lcol) * NE + lq * 8;
    f16x8 qf[16];
#pragma unroll
    for (int ks = 0; ks < 16; ks++) qf[ks] = *(const f16x8*)(qp + ks * 32);

    const _Float16* kbase = ksw + (size_t)rel * NS * NE;
    const _Float16* vbase = vsw + (size_t)rel * NS * NE;

    auto stageK = [&](int kc) {
        const _Float16* src = kbase + (size_t)kc * 64 * NE;
#pragma unroll
        for (int i = 0; i < 8; i++) {
            const int blk = i * 8 + w;                   // 1 KB block index
            gload_lds16(src + (size_t)blk * 512 + ln * 8, (_Float16*)Kb + blk * 512);
        }
    };
    auto stageV = [&](int kc) {
        const _Float16* src = vbase + (size_t)kc * NE * 64;
#pragma unroll
        for (int i = 0; i < 8; i++) {
            const int blk = i * 8 + w;
            gload_lds16(src + (size_t)blk * 512 + ln * 8, (_Float16*)Vb + blk * 512);
        }
    };

    f32x4 oacc[16] = {};
    float m_st[4] = {-1e30f, -1e30f, -1e30f, -1e30f};
    float l_st[4] = {0.f, 0.f, 0.f, 0.f};

    asm volatile("" ::: "memory");
    stageK(0);
    stageV(0);

    for (int kc = 0; kc < 64; kc++) {
        // K(t) done (V(t) / K(t+1) stay in flight); then cross-wave sync
        asm volatile("s_waitcnt vmcnt(8)" ::: "memory");
        __builtin_amdgcn_s_barrier();                    // A: K(t) visible
        asm volatile("" ::: "memory");

        // ---- QK^T: 16 q-rows x 32 keys (keys g*32..+32), K=512
        f32x4 s0 = {}, s1 = {};
        __builtin_amdgcn_s_setprio(1);
#pragma unroll
        for (int ks = 0; ks < 16; ks++) {
            const int ch = ((ks * 4 + lq) ^ xm) * 8;
            f16x8 kb0 = *(const f16x8*)&Kb[(g * 32 + lcol) * 512 + ch];
            f16x8 kb1 = *(const f16x8*)&Kb[(g * 32 + 16 + lcol) * 512 + ch];
            s0 = __builtin_amdgcn_mfma_f32_16x16x32_f16(qf[ks], kb0, s0, 0, 0, 0);
            s1 = __builtin_amdgcn_mfma_f32_16x16x32_f16(qf[ks], kb1, s1, 0, 0, 0);
        }
        __builtin_amdgcn_s_setprio(0);

        asm volatile("" ::: "memory");
        __builtin_amdgcn_s_barrier();                    // B: Kb free
        asm volatile("" ::: "memory");
        if (kc < 63) stageK(kc + 1);                     // overlaps softmax+PV

        // ---- wave-local folded softmax (rows lq*4+r, keys g*32 + {lcol,16+lcol})
        float Mg[4];
#pragma unroll
        for (int r = 0; r < 4; r++) {
            float mx = rmax16(fmaxf(s0[r], s1[r]));
            Mg[r] = fmaxf(m_st[r], mx);
            const float p0 = __expf(s0[r] - Mg[r]);
            const float p1 = __expf(s1[r] - Mg[r]);
            const int row = rt * 16 + lq * 4 + r;
            Pb[row * 72 + g * 32 + lcol]      = (_Float16)p0;
            Pb[row * 72 + g * 32 + 16 + lcol] = (_Float16)p1;
            const float ls = rsum16(p0 + p1);
            if (lcol == 0) { mpart[g][row] = Mg[r]; lpart[g][row] = ls; }
        }

        // V(t) done + own P/partial writes visible; then sync
        if (kc < 63) { asm volatile("s_waitcnt vmcnt(8) lgkmcnt(0)" ::: "memory"); }
        else         { asm volatile("s_waitcnt vmcnt(0) lgkmcnt(0)" ::: "memory"); }
        __builtin_amdgcn_s_barrier();                    // C: V(t), P, partials
        asm volatile("" ::: "memory");

        // ---- combine halves; update running state (state rows lq*4+r)
        float alpha[4];
#pragma unroll
        for (int r = 0; r < 4; r++) {
            const int row = rt * 16 + lq * 4 + r;
            const float M0 = mpart[0][row], M1 = mpart[1][row];
            const float mn = fmaxf(M0, M1);
            alpha[r] = __expf(m_st[r] - mn);
            l_st[r] = l_st[r] * alpha[r]
                    + __expf(M0 - mn) * lpart[0][row]
                    + __expf(M1 - mn) * lpart[1][row];
            m_st[r] = mn;
        }
        const bool allone = (alpha[0] == 1.f) & (alpha[1] == 1.f) &
                            (alpha[2] == 1.f) & (alpha[3] == 1.f);
        if (!__all(allone)) {
#pragma unroll
            for (int et = 0; et < 16; et++) {
                oacc[et][0] *= alpha[0]; oacc[et][1] *= alpha[1];
                oacc[et][2] *= alpha[2]; oacc[et][3] *= alpha[3];
            }
        }

        // ---- P A-fragment (rows = lcol): per-half correction exp(Mg - mn)
        const int frow = rt * 16 + lcol;
        const float F0 = mpart[0][frow], F1 = mpart[1][frow];
        const float fm = fmaxf(F0, F1);
        const _Float16 c0 = (_Float16)__expf(F0 - fm);
        const _Float16 c1 = (_Float16)__expf(F1 - fm);
        f16x8 pa0 = *(const f16x8*)&Pb[frow * 72 + lq * 8];
        f16x8 pa1 = *(const f16x8*)&Pb[frow * 72 + 32 + lq * 8];
#pragma unroll
        for (int j = 0; j < 8; j++) { pa0[j] *= c0; pa1[j] *= c1; }

        // ---- PV: rows rt*16..+16, E-cols g*256..+256, K=64
        __builtin_amdgcn_s_setprio(1);
#pragma unroll
        for (int et = 0; et < 16; et++) {
            const int e = g * 256 + et * 16 + lcol;
            f16x8 v0 = *(const f16x8*)&Vb[e * 64 + ((lq ^ xm) * 8)];
            f16x8 v1 = *(const f16x8*)&Vb[e * 64 + (((4 + lq) ^ xm) * 8)];
            oacc[et] = __builtin_amdgcn_mfma_f32_16x16x32_f16(pa0, v0, oacc[et], 0, 0, 0);
            oacc[et] = __builtin_amdgcn_mfma_f32_16x16x32_f16(pa1, v1, oacc[et], 0, 0, 0);
        }
        __builtin_amdgcn_s_setprio(0);

        asm volatile("" ::: "memory");
        __builtin_amdgcn_s_barrier();                    // D: Vb free
        asm volatile("" ::: "memory");
        if (kc < 63) stageV(kc + 1);                     // overlaps next QK
    }

#pragma unroll
    for (int r = 0; r < 4; r++) {
        const float inv = 1.0f / l_st[r];
        const size_t ob = ((size_t)babs * NS + q0 + rt * 16 + lq * 4 + r) * NE + g * 256 + lcol;
#pragma unroll
        for (int et = 0; et < 16; et++)
            out[ob + et * 16] = oacc[et][r] * inv;
    }
}

extern "C" void kernel_launch(void* const* d_in, const int* in_sizes, int n_in,
                              void* d_out, int out_size, void* d_ws, size_t ws_size,
                              hipStream_t stream) {
    const float* query = (const float*)d_in[0];
    const float* key_  = (const float*)d_in[1];
    const float* value = (const float*)d_in[2];
    const float* Wq    = (const float*)d_in[3];
    const float* bq    = (const float*)d_in[4];
    const float* Wk    = (const float*)d_in[5];
    const float* bk    = (const float*)d_in[6];
    const float* Wv    = (const float*)d_in[7];
    const float* bv    = (const float*)d_in[8];

    const size_t per_batch = (size_t)3 * NS * NE * 2;   // q + k_sw + v_sw f16 = 12 MiB
    int nb_chunk = (int)(ws_size / per_batch);
    if (nb_chunk > NB) nb_chunk = NB;
    if (nb_chunk < 1)  nb_chunk = 1;

    _Float16* qh  = (_Float16*)d_ws;
    _Float16* kh  = qh + (size_t)nb_chunk * NS * NE;
    _Float16* vth = kh + (size_t)nb_chunk * NS * NE;

    for (int b0 = 0; b0 < NB; b0 += nb_chunk) {
        int nb = NB - b0 < nb_chunk ? NB - b0 : nb_chunk;
        proj_kernel<<<dim3(nb * 128, 3, 1), 256, 0, stream>>>(
            query, key_, value, Wq, Wk, Wv, bq, bk, bv, qh, kh, vth, b0);
        attn_kernel<<<dim3(NS / 64, nb, 1), 512, 0, stream>>>(
            qh, kh, vth, (float*)d_out, b0);
    }
}

// Round 9
// 445.557 us; speedup vs baseline: 1.4386x; 1.0080x over previous
//
#include <hip/hip_runtime.h>

typedef __attribute__((ext_vector_type(8))) _Float16 f16x8;
typedef __attribute__((ext_vector_type(4))) _Float16 f16x4;
typedef __attribute__((ext_vector_type(4))) float f32x4;

#define NB 4
#define NS 4096
#define NE 512

__device__ __forceinline__ f16x8 cvt2(float4 a, float4 b) {
    f16x8 r;
    r[0] = (_Float16)a.x; r[1] = (_Float16)a.y; r[2] = (_Float16)a.z; r[3] = (_Float16)a.w;
    r[4] = (_Float16)b.x; r[5] = (_Float16)b.y; r[6] = (_Float16)b.z; r[7] = (_Float16)b.w;
    return r;
}
__device__ __forceinline__ void gload_lds16(const void* g, void* l) {
    __builtin_amdgcn_global_load_lds(
        (const __attribute__((address_space(1))) void*)g,
        (__attribute__((address_space(3))) void*)l, 16, 0, 0);
}

// DPP ring reductions over the 16-lane row (pure VALU, no DS latency).
template <int CTRL>
__device__ __forceinline__ float dpp_ror(float x) {
    int r = __builtin_amdgcn_update_dpp(
        0, __builtin_bit_cast(int, x), CTRL, 0xF, 0xF, true);
    return __builtin_bit_cast(float, r);
}
__device__ __forceinline__ float rmax16(float x) {
    x = fmaxf(x, dpp_ror<0x128>(x));   // row_ror:8
    x = fmaxf(x, dpp_ror<0x124>(x));   // row_ror:4
    x = fmaxf(x, dpp_ror<0x122>(x));   // row_ror:2
    x = fmaxf(x, dpp_ror<0x121>(x));   // row_ror:1
    return x;
}
__device__ __forceinline__ float rsum16(float x) {
    x += dpp_ror<0x128>(x);
    x += dpp_ror<0x124>(x);
    x += dpp_ror<0x122>(x);
    x += dpp_ror<0x121>(x);
    return x;
}

// ---------------- Stage 1: fused QKV projection (fp32 in, f16 out) ------
// v12: raw-barrier pipelined staging. __syncthreads() drains vmcnt(0) at
// every barrier (compiler semantics), which defeated v11's prefetch — so
// the loop now uses raw s_barrier + counted waits: LDS double-buffer,
// register ping-pong, ONE barrier per K-tile, loads issued 2 tiles ahead,
// vmcnt(0) consumed after a full compute phase (hidden).
// q: natural [row][e]. k: swizzled rows — element (s,e) at s*512 + ((e/8)^(s&7))*8 + e%8.
// v: chunked+swizzled [b][kc][e][64]: (d,s) at ((b*64+kc)*512+d)*64 + (((s&63)/8)^(d&7))*8 + s%8.
__global__ __launch_bounds__(256, 2) void proj_kernel(
    const float* __restrict__ Xq, const float* __restrict__ Xk,
    const float* __restrict__ Xv,
    const float* __restrict__ Wq, const float* __restrict__ Wk,
    const float* __restrict__ Wv,
    const float* __restrict__ bq, const float* __restrict__ bk,
    const float* __restrict__ bv,
    _Float16* __restrict__ oq, _Float16* __restrict__ ok,
    _Float16* __restrict__ ovt, int b0)
{
    __shared__ __align__(16) _Float16 As[2][128 * 32];
    __shared__ __align__(16) _Float16 Bs[2][128 * 32];
    const int t = threadIdx.x;
    const int w = t >> 6, ln = t & 63;
    const int which = blockIdx.y;
    const float* X    = (which == 0) ? Xq : ((which == 1) ? Xk : Xv);
    const float* W    = (which == 0) ? Wq : ((which == 1) ? Wk : Wv);
    const float* bias = (which == 0) ? bq : ((which == 1) ? bk : bv);

    const int m0 = (blockIdx.x >> 2) * 128;
    const int n0 = (blockIdx.x & 3) * 128;

    const int srow  = t >> 1;
    const int shalf = (t & 1) * 16;
    const float* gA = X + ((size_t)b0 * NS + m0 + srow) * NE + shalf;
    const float* gB = W + (size_t)(n0 + srow) * NE + shalf;

    f32x4 acc[4][4] = {};
    const int wm = (w >> 1) * 64, wn = (w & 1) * 64;
    const int lcol = ln & 15, lq = ln >> 4;

    float4 ra[4], rb[4], na[4], nb[4];

    auto LOAD = [&](int k0, float4* da, float4* db) {
        da[0] = *(const float4*)(gA + k0);
        da[1] = *(const float4*)(gA + k0 + 4);
        da[2] = *(const float4*)(gA + k0 + 8);
        da[3] = *(const float4*)(gA + k0 + 12);
        db[0] = *(const float4*)(gB + k0);
        db[1] = *(const float4*)(gB + k0 + 4);
        db[2] = *(const float4*)(gB + k0 + 8);
        db[3] = *(const float4*)(gB + k0 + 12);
    };
    auto WRITE = [&](int p, const float4* da, const float4* db) {
        *(f16x8*)&As[p][srow * 32 + shalf]     = cvt2(da[0], da[1]);
        *(f16x8*)&As[p][srow * 32 + shalf + 8] = cvt2(da[2], da[3]);
        *(f16x8*)&Bs[p][srow * 32 + shalf]     = cvt2(db[0], db[1]);
        *(f16x8*)&Bs[p][srow * 32 + shalf + 8] = cvt2(db[2], db[3]);
    };
    auto COMPUTE = [&](int p) {
        f16x8 a[4], b[4];
#pragma unroll
        for (int i = 0; i < 4; i++)
            a[i] = *(const f16x8*)&As[p][(wm + i * 16 + lcol) * 32 + lq * 8];
#pragma unroll
        for (int j = 0; j < 4; j++)
            b[j] = *(const f16x8*)&Bs[p][(wn + j * 16 + lcol) * 32 + lq * 8];
#pragma unroll
        for (int i = 0; i < 4; i++)
#pragma unroll
            for (int j = 0; j < 4; j++)
                acc[i][j] = __builtin_amdgcn_mfma_f32_16x16x32_f16(a[i], b[j], acc[i][j], 0, 0, 0);
    };

    // prologue: tile0 -> buf0, tile1 -> na (in flight)
    LOAD(0, ra, rb);
    asm volatile("s_waitcnt vmcnt(0)" ::: "memory");
    WRITE(0, ra, rb);
    LOAD(32, na, nb);
    asm volatile("s_waitcnt lgkmcnt(0)" ::: "memory");
    __builtin_amdgcn_s_barrier();                   // buf0 visible
    asm volatile("" ::: "memory");

#pragma unroll
    for (int kk = 0; kk < 8; kk++) {
        // ---- tile 2kk from buf0; stage 2kk+1 (na) -> buf1; load 2kk+2 -> ra
        COMPUTE(0);
        asm volatile("s_waitcnt vmcnt(0)" ::: "memory");   // na ready (hidden)
        WRITE(1, na, nb);
        if (2 * kk + 2 < 16) LOAD((2 * kk + 2) * 32, ra, rb);
        asm volatile("s_waitcnt lgkmcnt(0)" ::: "memory");
        __builtin_amdgcn_s_barrier();               // buf1 visible, buf0 free
        asm volatile("" ::: "memory");
        // ---- tile 2kk+1 from buf1; stage 2kk+2 (ra) -> buf0; load 2kk+3 -> na
        COMPUTE(1);
        if (2 * kk + 2 < 16) {
            asm volatile("s_waitcnt vmcnt(0)" ::: "memory");
            WRITE(0, ra, rb);
            if (2 * kk + 3 < 16) LOAD((2 * kk + 3) * 32, na, nb);
            asm volatile("s_waitcnt lgkmcnt(0)" ::: "memory");
            __builtin_amdgcn_s_barrier();           // buf0 visible, buf1 free
            asm volatile("" ::: "memory");
        }
    }

    // C/D layout: col = lane&15, row = (lane>>4)*4 + reg
    if (which == 0) {
#pragma unroll
        for (int j = 0; j < 4; j++) {
            const int col = n0 + wn + j * 16 + lcol;
            const float bb = bias[col];
#pragma unroll
            for (int i = 0; i < 4; i++) {
                const int rbase = m0 + wm + i * 16 + lq * 4;
#pragma unroll
                for (int r = 0; r < 4; r++)
                    oq[(size_t)(rbase + r) * NE + col] = (_Float16)(acc[i][j][r] + bb);
            }
        }
    } else if (which == 1) {
#pragma unroll
        for (int j = 0; j < 4; j++) {
            const int col = n0 + wn + j * 16 + lcol;
            const int cch = col >> 3, clo = col & 7;
            const float bb = bias[col];
#pragma unroll
            for (int i = 0; i < 4; i++) {
                const int rbase = m0 + wm + i * 16 + lq * 4;
#pragma unroll
                for (int r = 0; r < 4; r++) {
                    const int s = rbase + r;
                    ok[(size_t)s * NE + ((cch ^ (s & 7)) << 3) + clo] =
                        (_Float16)(acc[i][j][r] + bb);
                }
            }
        }
    } else {
#pragma unroll
        for (int j = 0; j < 4; j++) {
            const int d = n0 + wn + j * 16 + lcol;
            const float bb = bias[d];
#pragma unroll
            for (int i = 0; i < 4; i++) {
                const int rbase = m0 + wm + i * 16 + lq * 4;
                const int bat = rbase >> 12;
                const int sl  = rbase & 4095;
                const int kc  = sl >> 6;
                const int slot = ((sl >> 3) & 7) ^ (d & 7);
                f16x4 pk;
#pragma unroll
                for (int r = 0; r < 4; r++) pk[r] = (_Float16)(acc[i][j][r] + bb);
                *(f16x4*)&ovt[(((size_t)bat * 64 + kc) * NE + d) * 64 + slot * 8 + (sl & 7)] = pk;
            }
        }
    }
}

// ---------------- Stage 2: flash attention v10 (unchanged) --------------
// v5 skeleton (KB=64, 8 waves, 64 iters, 1 block/CU) with the serial chain
// removed: (1) split K/V staging in single buffers with counted vmcnt(8);
// (2) DPP ring reductions; (3) folded-max softmax with per-half correction
// on the A-fragment. 4 barriers/iter, no in-loop vmcnt(0) drain.
// wave w: rt=w&3 (16 q-rows); g=w>>2: QK keys [g*32,+32), PV E [g*256,+256).
__global__ __launch_bounds__(512, 2) void attn_kernel(
    const _Float16* __restrict__ q, const _Float16* __restrict__ ksw,
    const _Float16* __restrict__ vsw, float* __restrict__ out, int b0)
{
    __shared__ __align__(16) _Float16 Kb[64 * 512];
    __shared__ __align__(16) _Float16 Vb[512 * 64];
    __shared__ __align__(16) _Float16 Pb[64 * 72];
    __shared__ float mpart[2][64];
    __shared__ float lpart[2][64];

    const int t = threadIdx.x, w = t >> 6, ln = t & 63;
    const int lcol = ln & 15, lq = ln >> 4;
    const int rt = w & 3, g = w >> 2;
    const int xm = lcol & 7;

    // XCD-aware swizzle (proven: FETCH 139->41 MB): 2 XCDs per batch
    int qx, rel;
    if (gridDim.y == 4) {
        const int id = blockIdx.x + (blockIdx.y << 6);   // 0..255, hw xcd = id&7
        const int xcd = id & 7, slot = id >> 3;          // slot 0..31
        rel = xcd >> 1;
        qx  = ((xcd & 1) << 5) + slot;
    } else { qx = blockIdx.x; rel = blockIdx.y; }
    const int babs = b0 + rel;
    const int q0 = qx * 64;

    const _Float16* qp = q + ((size_t)rel * NS + q0 + rt * 16 + lcol) * NE + lq * 8;
    f16x8 qf[16];
#pragma unroll
    for (int ks = 0; ks < 16; ks++) qf[ks] = *(const f16x8*)(qp + ks * 32);

    const _Float16* kbase = ksw + (size_t)rel * NS * NE;
    const _Float16* vbase = vsw + (size_t)rel * NS * NE;

    auto stageK = [&](int kc) {
        const _Float16* src = kbase + (size_t)kc * 64 * NE;
#pragma unroll
        for (int i = 0; i < 8; i++) {
            const int blk = i * 8 + w;                   // 1 KB block index
            gload_lds16(src + (size_t)blk * 512 + ln * 8, (_Float16*)Kb + blk * 512);
        }
    };
    auto stageV = [&](int kc) {
        const _Float16* src = vbase + (size_t)kc * NE * 64;
#pragma unroll
        for (int i = 0; i < 8; i++) {
            const int blk = i * 8 + w;
            gload_lds16(src + (size_t)blk * 512 + ln * 8, (_Float16*)Vb + blk * 512);
        }
    };

    f32x4 oacc[16] = {};
    float m_st[4] = {-1e30f, -1e30f, -1e30f, -1e30f};
    float l_st[4] = {0.f, 0.f, 0.f, 0.f};

    asm volatile("" ::: "memory");
    stageK(0);
    stageV(0);

    for (int kc = 0; kc < 64; kc++) {
        // K(t) done (V(t) / K(t+1) stay in flight); then cross-wave sync
        asm volatile("s_waitcnt vmcnt(8)" ::: "memory");
        __builtin_amdgcn_s_barrier();                    // A: K(t) visible
        asm volatile("" ::: "memory");

        // ---- QK^T: 16 q-rows x 32 keys (keys g*32..+32), K=512
        f32x4 s0 = {}, s1 = {};
        __builtin_amdgcn_s_setprio(1);
#pragma unroll
        for (int ks = 0; ks < 16; ks++) {
            const int ch = ((ks * 4 + lq) ^ xm) * 8;
            f16x8 kb0 = *(const f16x8*)&Kb[(g * 32 + lcol) * 512 + ch];
            f16x8 kb1 = *(const f16x8*)&Kb[(g * 32 + 16 + lcol) * 512 + ch];
            s0 = __builtin_amdgcn_mfma_f32_16x16x32_f16(qf[ks], kb0, s0, 0, 0, 0);
            s1 = __builtin_amdgcn_mfma_f32_16x16x32_f16(qf[ks], kb1, s1, 0, 0, 0);
        }
        __builtin_amdgcn_s_setprio(0);

        asm volatile("" ::: "memory");
        __builtin_amdgcn_s_barrier();                    // B: Kb free
        asm volatile("" ::: "memory");
        if (kc < 63) stageK(kc + 1);                     // overlaps softmax+PV

        // ---- wave-local folded softmax (rows lq*4+r, keys g*32 + {lcol,16+lcol})
        float Mg[4];
#pragma unroll
        for (int r = 0; r < 4; r++) {
            float mx = rmax16(fmaxf(s0[r], s1[r]));
            Mg[r] = fmaxf(m_st[r], mx);
            const float p0 = __expf(s0[r] - Mg[r]);
            const float p1 = __expf(s1[r] - Mg[r]);
            const int row = rt * 16 + lq * 4 + r;
            Pb[row * 72 + g * 32 + lcol]      = (_Float16)p0;
            Pb[row * 72 + g * 32 + 16 + lcol] = (_Float16)p1;
            const float ls = rsum16(p0 + p1);
            if (lcol == 0) { mpart[g][row] = Mg[r]; lpart[g][row] = ls; }
        }

        // V(t) done + own P/partial writes visible; then sync
        if (kc < 63) { asm volatile("s_waitcnt vmcnt(8) lgkmcnt(0)" ::: "memory"); }
        else         { asm volatile("s_waitcnt vmcnt(0) lgkmcnt(0)" ::: "memory"); }
        __builtin_amdgcn_s_barrier();                    // C: V(t), P, partials
        asm volatile("" ::: "memory");

        // ---- combine halves; update running state (state rows lq*4+r)
        float alpha[4];
#pragma unroll
        for (int r = 0; r < 4; r++) {
            const int row = rt * 16 + lq * 4 + r;
            const float M0 = mpart[0][row], M1 = mpart[1][row];
            const float mn = fmaxf(M0, M1);
            alpha[r] = __expf(m_st[r] - mn);
            l_st[r] = l_st[r] * alpha[r]
                    + __expf(M0 - mn) * lpart[0][row]
                    + __expf(M1 - mn) * lpart[1][row];
            m_st[r] = mn;
        }
        const bool allone = (alpha[0] == 1.f) & (alpha[1] == 1.f) &
                            (alpha[2] == 1.f) & (alpha[3] == 1.f);
        if (!__all(allone)) {
#pragma unroll
            for (int et = 0; et < 16; et++) {
                oacc[et][0] *= alpha[0]; oacc[et][1] *= alpha[1];
                oacc[et][2] *= alpha[2]; oacc[et][3] *= alpha[3];
            }
        }

        // ---- P A-fragment (rows = lcol): per-half correction exp(Mg - mn)
        const int frow = rt * 16 + lcol;
        const float F0 = mpart[0][frow], F1 = mpart[1][frow];
        const float fm = fmaxf(F0, F1);
        const _Float16 c0 = (_Float16)__expf(F0 - fm);
        const _Float16 c1 = (_Float16)__expf(F1 - fm);
        f16x8 pa0 = *(const f16x8*)&Pb[frow * 72 + lq * 8];
        f16x8 pa1 = *(const f16x8*)&Pb[frow * 72 + 32 + lq * 8];
#pragma unroll
        for (int j = 0; j < 8; j++) { pa0[j] *= c0; pa1[j] *= c1; }

        // ---- PV: rows rt*16..+16, E-cols g*256..+256, K=64
        __builtin_amdgcn_s_setprio(1);
#pragma unroll
        for (int et = 0; et < 16; et++) {
            const int e = g * 256 + et * 16 + lcol;
            f16x8 v0 = *(const f16x8*)&Vb[e * 64 + ((lq ^ xm) * 8)];
            f16x8 v1 = *(const f16x8*)&Vb[e * 64 + (((4 + lq) ^ xm) * 8)];
            oacc[et] = __builtin_amdgcn_mfma_f32_16x16x32_f16(pa0, v0, oacc[et], 0, 0, 0);
            oacc[et] = __builtin_amdgcn_mfma_f32_16x16x32_f16(pa1, v1, oacc[et], 0, 0, 0);
        }
        __builtin_amdgcn_s_setprio(0);

        asm volatile("" ::: "memory");
        __builtin_amdgcn_s_barrier();                    // D: Vb free
        asm volatile("" ::: "memory");
        if (kc < 63) stageV(kc + 1);                     // overlaps next QK
    }

#pragma unroll
    for (int r = 0; r < 4; r++) {
        const float inv = 1.0f / l_st[r];
        const size_t ob = ((size_t)babs * NS + q0 + rt * 16 + lq * 4 + r) * NE + g * 256 + lcol;
#pragma unroll
        for (int et = 0; et < 16; et++)
            out[ob + et * 16] = oacc[et][r] * inv;
    }
}

extern "C" void kernel_launch(void* const* d_in, const int* in_sizes, int n_in,
                              void* d_out, int out_size, void* d_ws, size_t ws_size,
                              hipStream_t stream) {
    const float* query = (const float*)d_in[0];
    const float* key_  = (const float*)d_in[1];
    const float* value = (const float*)d_in[2];
    const float* Wq    = (const float*)d_in[3];
    const float* bq    = (const float*)d_in[4];
    const float* Wk    = (const float*)d_in[5];
    const float* bk    = (const float*)d_in[6];
    const float* Wv    = (const float*)d_in[7];
    const float* bv    = (const float*)d_in[8];

    const size_t per_batch = (size_t)3 * NS * NE * 2;   // q + k_sw + v_sw f16 = 12 MiB
    int nb_chunk = (int)(ws_size / per_batch);
    if (nb_chunk > NB) nb_chunk = NB;
    if (nb_chunk < 1)  nb_chunk = 1;

    _Float16* qh  = (_Float16*)d_ws;
    _Float16* kh  = qh + (size_t)nb_chunk * NS * NE;
    _Float16* vth = kh + (size_t)nb_chunk * NS * NE;

    for (int b0 = 0; b0 < NB; b0 += nb_chunk) {
        int nb = NB - b0 < nb_chunk ? NB - b0 : nb_chunk;
        proj_kernel<<<dim3(nb * 128, 3, 1), 256, 0, stream>>>(
            query, key_, value, Wq, Wk, Wv, bq, bk, bv, qh, kh, vth, b0);
        attn_kernel<<<dim3(NS / 64, nb, 1), 512, 0, stream>>>(
            qh, kh, vth, (float*)d_out, b0);
    }
}